// Round 1
// baseline (136.536 us; speedup 1.0000x reference)
//
#include <hip/hip_runtime.h>

// LocalAggregator: semantic splatting of P=2048 3D Gaussians onto a 60x60x36
// voxel grid (N=129600 points), C=13 channels.
//
// Strategy:
//   Kernel 1: per-Gaussian precompute (inverse covariance, int bin, radius,
//             opacity, semantics) into a 28-float AoS record in d_ws.
//   Kernel 2: one block per 4x4(xy)-column x 36(z) tile (225 blocks, 576 thr,
//             1 thread = 1 voxel). Block culls all Gaussians vs. the tile's
//             integer bbox, compacts survivors to LDS, then evaluates them in
//             LDS-staged batches (broadcast reads). Only ~150/2048 Gaussians
//             survive per tile -> ~14x fewer pair evaluations than dense.

constexpr int   HH      = 60;
constexpr int   WW      = 60;
constexpr int   DD      = 36;
constexpr int   P_N     = 2048;
constexpr int   C_N     = 13;
constexpr int   REC     = 28;     // floats per Gaussian record (7 x float4)
constexpr int   BATCH   = 128;    // Gaussians staged in LDS at a time
constexpr float GRID_SZ = 0.08f;

__global__ void precompute_kernel(const float* __restrict__ means,
                                  const float* __restrict__ opac,
                                  const float* __restrict__ sem,
                                  const float* __restrict__ scales,
                                  const float* __restrict__ cov,
                                  const float* __restrict__ origin,
                                  float* __restrict__ recs) {
    int g = blockIdx.x * blockDim.x + threadIdx.x;
    if (g >= P_N) return;
    float mx = means[g * 3 + 0], my = means[g * 3 + 1], mz = means[g * 3 + 2];
    float sx = scales[g * 3 + 0], sy = scales[g * 3 + 1], sz = scales[g * 3 + 2];
    float smax = fmaxf(sx, fmaxf(sy, sz));
    int rad = (int)ceilf(smax * 3.0f / GRID_SZ);
    float ox = origin[0], oy = origin[1], oz = origin[2];
    // match reference: ((means - origin) / GRID).astype(int32)  (trunc toward 0)
    int mix = (int)((mx - ox) / GRID_SZ);
    int miy = (int)((my - oy) / GRID_SZ);
    int miz = (int)((mz - oz) / GRID_SZ);
    const float* cv = cov + g * 9;
    // packed = (xx, yy, zz, xy, yz, xz) = flat indices [0,4,8,1,5,2]
    float a = cv[0], b = cv[4], c = cv[8], d = cv[1], e = cv[5], f = cv[2];
    float det = a * (b * c - e * e) - d * (d * c - e * f) + f * (d * e - b * f);
    float* r = recs + g * REC;
    r[0]  = mx; r[1] = my; r[2] = mz;
    r[3]  = opac[g];
    r[4]  = (b * c - e * e) / det;   // ixx
    r[5]  = (a * c - f * f) / det;   // iyy
    r[6]  = (a * b - d * d) / det;   // izz
    r[7]  = (e * f - d * c) / det;   // ixy
    r[8]  = (d * f - a * e) / det;   // iyz
    r[9]  = (d * e - b * f) / det;   // ixz
    r[10] = __int_as_float(mix);
    r[11] = __int_as_float(miy);
    r[12] = __int_as_float(miz);
    r[13] = __int_as_float(rad);
#pragma unroll
    for (int cc = 0; cc < C_N; ++cc) r[14 + cc] = sem[g * C_N + cc];
    r[27] = 0.0f;
}

__global__ __launch_bounds__(576) void agg_kernel(const float* __restrict__ recs,
                                                  const float* __restrict__ origin,
                                                  float* __restrict__ out) {
    __shared__ int   s_list[P_N];
    __shared__ float s_rec[BATCH][REC];
    __shared__ int   s_cnt;

    const int tix = (int)blockIdx.x % (HH / 4);
    const int tiy = (int)blockIdx.x / (HH / 4);
    const int i0 = tix * 4, j0 = tiy * 4;

    if (threadIdx.x == 0) s_cnt = 0;
    __syncthreads();

    // --- cull: Gaussian int-box vs tile bbox ---
    for (int g = (int)threadIdx.x; g < P_N; g += (int)blockDim.x) {
        const float* r = recs + g * REC;
        int mx  = __float_as_int(r[10]);
        int my  = __float_as_int(r[11]);
        int mz  = __float_as_int(r[12]);
        int rad = __float_as_int(r[13]);
        bool ov = (mx - rad <= i0 + 3) && (mx + rad >= i0)
               && (my - rad <= j0 + 3) && (my + rad >= j0)
               && (mz - rad <= DD - 1) && (mz + rad >= 0);
        if (ov) {
            int idx = atomicAdd(&s_cnt, 1);
            s_list[idx] = g;
        }
    }
    __syncthreads();
    const int cnt = s_cnt;

    // --- this thread's voxel ---
    const int k  = (int)threadIdx.x % DD;
    const int lj = ((int)threadIdx.x / DD) & 3;
    const int li = (int)threadIdx.x / (DD * 4);
    const int gi = i0 + li, gj = j0 + lj;
    // bit-exact replication of reference pts = ((i)+0.5f)*GRID in fp32
    const float px = ((float)gi + 0.5f) * GRID_SZ;
    const float py = ((float)gj + 0.5f) * GRID_SZ;
    const float pz = ((float)k  + 0.5f) * GRID_SZ;
    const float ox = origin[0], oy = origin[1], oz = origin[2];
    const int pix = (int)((px - ox) / GRID_SZ);
    const int piy = (int)((py - oy) / GRID_SZ);
    const int piz = (int)((pz - oz) / GRID_SZ);

    float acc[C_N];
#pragma unroll
    for (int cc = 0; cc < C_N; ++cc) acc[cc] = 0.0f;

    // --- evaluate surviving Gaussians in LDS-staged batches ---
    for (int base = 0; base < cnt; base += BATCH) {
        int nb = min(BATCH, cnt - base);
        __syncthreads();
        for (int t = (int)threadIdx.x; t < nb * 7; t += (int)blockDim.x) {
            int rg = t / 7, part = t % 7;
            int g = s_list[base + rg];
            ((float4*)&s_rec[rg][0])[part] =
                ((const float4*)(recs + (long)g * REC))[part];
        }
        __syncthreads();
        for (int b2 = 0; b2 < nb; ++b2) {
            const float* r = s_rec[b2];
            float dx = px - r[0], dy = py - r[1], dz = pz - r[2];
            int mx  = __float_as_int(r[10]);
            int my  = __float_as_int(r[11]);
            int mzz = __float_as_int(r[12]);
            int rad = __float_as_int(r[13]);
            bool inbox = (abs(pix - mx) <= rad)
                      && (abs(piy - my) <= rad)
                      && (abs(piz - mzz) <= rad);
            float quad = r[4] * dx * dx + r[5] * dy * dy + r[6] * dz * dz
                       + 2.0f * (r[7] * dx * dy + r[8] * dy * dz + r[9] * dx * dz);
            float w = r[3] * __expf(-0.5f * quad);
            w = inbox ? w : 0.0f;
#pragma unroll
            for (int cc = 0; cc < C_N; ++cc)
                acc[cc] = fmaf(w, r[14 + cc], acc[cc]);
        }
    }

    // --- write out [N, C] fp32 ---
    const int n = gi * (WW * DD) + gj * DD + k;
    float* op = out + (long)n * C_N;
#pragma unroll
    for (int cc = 0; cc < C_N; ++cc) op[cc] = acc[cc];
}

extern "C" void kernel_launch(void* const* d_in, const int* in_sizes, int n_in,
                              void* d_out, int out_size, void* d_ws, size_t ws_size,
                              hipStream_t stream) {
    const float* means  = (const float*)d_in[1];
    const float* opac   = (const float*)d_in[2];
    const float* sem    = (const float*)d_in[3];
    const float* scales = (const float*)d_in[4];
    const float* cov    = (const float*)d_in[5];
    const float* origin = (const float*)d_in[6];
    float* out  = (float*)d_out;
    float* recs = (float*)d_ws;   // needs P_N*REC*4 = 224 KiB

    precompute_kernel<<<(P_N + 255) / 256, 256, 0, stream>>>(
        means, opac, sem, scales, cov, origin, recs);
    agg_kernel<<<(HH / 4) * (WW / 4), 576, 0, stream>>>(recs, origin, out);
}

// Round 2
// 113.499 us; speedup vs baseline: 1.2030x; 1.2030x over previous
//
#include <hip/hip_runtime.h>

// LocalAggregator: semantic splatting of P=2048 3D Gaussians onto a 60x60x36
// voxel grid (N=129600 points), C=13 channels.
//
// Round 2 strategy:
//   Kernel 1: per-Gaussian precompute. Record = 24 floats
//             [mean(3), log2(opac), -0.5*log2e*icov(6, off-diags x2), sem(13), pad]
//             plus a separate int4 box array (m_int, radius) for cheap culling.
//   Kernel 2: block = 4x4(xy) x 12(z) voxels, 192 threads (3 waves), grid =
//             15*15*3 = 675 blocks (~2.6 blocks/CU -> all CUs busy, short tail).
//             Block culls the 2048 Gaussians against its xyz bbox (z-window 12
//             now culled too!), compacts to LDS, stages survivor records in LDS
//             batches. Each wave owns a 4-z slab: per survivor it reads only the
//             16B box, and __ballot-skips the quad/exp/FMA body when no lane's
//             voxel is inside the Gaussian's int box (~32% skip on survivors).

constexpr int   HH      = 60;
constexpr int   WW      = 60;
constexpr int   DD      = 36;
constexpr int   P_N     = 2048;
constexpr int   C_N     = 13;
constexpr int   REC     = 24;     // floats per Gaussian record (6 x float4)
constexpr int   BATCH   = 128;    // Gaussians staged in LDS at a time
constexpr int   ZCH     = 12;     // z-extent per block
constexpr int   TPB     = 192;    // 3 waves
constexpr float GRID_SZ = 0.08f;

__global__ void precompute_kernel(const float* __restrict__ means,
                                  const float* __restrict__ opac,
                                  const float* __restrict__ sem,
                                  const float* __restrict__ scales,
                                  const float* __restrict__ cov,
                                  const float* __restrict__ origin,
                                  float* __restrict__ recs,
                                  int4* __restrict__ boxes) {
    int g = blockIdx.x * blockDim.x + threadIdx.x;
    if (g >= P_N) return;
    float mx = means[g * 3 + 0], my = means[g * 3 + 1], mz = means[g * 3 + 2];
    float sx = scales[g * 3 + 0], sy = scales[g * 3 + 1], sz = scales[g * 3 + 2];
    float smax = fmaxf(sx, fmaxf(sy, sz));
    int rad = (int)ceilf(smax * 3.0f / GRID_SZ);
    float ox = origin[0], oy = origin[1], oz = origin[2];
    // match reference: ((means - origin) / GRID).astype(int32)  (trunc toward 0)
    int mix = (int)((mx - ox) / GRID_SZ);
    int miy = (int)((my - oy) / GRID_SZ);
    int miz = (int)((mz - oz) / GRID_SZ);
    const float* cv = cov + g * 9;
    // packed = (xx, yy, zz, xy, yz, xz) = flat indices [0,4,8,1,5,2]
    float a = cv[0], b = cv[4], c = cv[8], d = cv[1], e = cv[5], f = cv[2];
    float det = a * (b * c - e * e) - d * (d * c - e * f) + f * (d * e - b * f);
    const float kD = -0.5f * 1.44269504088896340736f;  // -0.5 * log2(e)
    const float kO = -1.44269504088896340736f;         // fold the 2x off-diag
    float* r = recs + g * REC;
    r[0] = mx; r[1] = my; r[2] = mz;
    r[3] = __log2f(opac[g]);
    r[4] = kD * (b * c - e * e) / det;   // c_xx
    r[5] = kD * (a * c - f * f) / det;   // c_yy
    r[6] = kD * (a * b - d * d) / det;   // c_zz
    r[7] = kO * (e * f - d * c) / det;   // c_xy
    r[8] = kO * (d * f - a * e) / det;   // c_yz
    r[9] = kO * (d * e - b * f) / det;   // c_xz
#pragma unroll
    for (int cc = 0; cc < C_N; ++cc) r[10 + cc] = sem[g * C_N + cc];
    r[23] = 0.0f;
    boxes[g] = make_int4(mix, miy, miz, rad);
}

__global__ __launch_bounds__(TPB) void agg_kernel(const float* __restrict__ recs,
                                                  const int4* __restrict__ boxes,
                                                  const float* __restrict__ origin,
                                                  float* __restrict__ out) {
    __shared__ int   s_list[P_N];
    __shared__ int4  s_box[BATCH];
    __shared__ float s_rec[BATCH][REC];
    __shared__ int   s_cnt;

    const int bz  = (int)blockIdx.x % (DD / ZCH);     // 0..2
    const int txy = (int)blockIdx.x / (DD / ZCH);
    const int tix = txy % (HH / 4);
    const int tiy = txy / (HH / 4);
    const int i0 = tix * 4, j0 = tiy * 4, z0 = bz * ZCH;

    if (threadIdx.x == 0) s_cnt = 0;
    __syncthreads();

    // --- cull: Gaussian int-box vs this block's xyz bbox ---
    for (int g = (int)threadIdx.x; g < P_N; g += TPB) {
        int4 bx = boxes[g];
        bool ov = (bx.x - bx.w <= i0 + 3)       && (bx.x + bx.w >= i0)
               && (bx.y - bx.w <= j0 + 3)       && (bx.y + bx.w >= j0)
               && (bx.z - bx.w <= z0 + ZCH - 1) && (bx.z + bx.w >= z0);
        if (ov) {
            int idx = atomicAdd(&s_cnt, 1);
            s_list[idx] = g;
        }
    }
    __syncthreads();
    const int cnt = s_cnt;

    // --- this thread's voxel: wave w owns z slab [z0+4w, z0+4w+3], 16 xy ---
    const int wave = (int)threadIdx.x / 64;
    const int lane = (int)threadIdx.x % 64;
    const int kk = lane / 16;
    const int xy = lane % 16;
    const int li = xy / 4, lj = xy % 4;
    const int gi = i0 + li, gj = j0 + lj, k = z0 + wave * 4 + kk;
    // bit-exact replication of reference pts = (i + 0.5f) * GRID in fp32
    const float px = ((float)gi + 0.5f) * GRID_SZ;
    const float py = ((float)gj + 0.5f) * GRID_SZ;
    const float pz = ((float)k  + 0.5f) * GRID_SZ;
    const float ox = origin[0], oy = origin[1], oz = origin[2];
    const int pix = (int)((px - ox) / GRID_SZ);
    const int piy = (int)((py - oy) / GRID_SZ);
    const int piz = (int)((pz - oz) / GRID_SZ);

    float acc[C_N];
#pragma unroll
    for (int cc = 0; cc < C_N; ++cc) acc[cc] = 0.0f;

    // --- evaluate surviving Gaussians in LDS-staged batches ---
    for (int base = 0; base < cnt; base += BATCH) {
        int nb = min(BATCH, cnt - base);
        __syncthreads();
        for (int t = (int)threadIdx.x; t < nb; t += TPB)
            s_box[t] = boxes[s_list[base + t]];
        for (int t = (int)threadIdx.x; t < nb * 6; t += TPB) {
            int rg = t / 6, part = t % 6;
            int g = s_list[base + rg];
            ((float4*)&s_rec[rg][0])[part] =
                ((const float4*)(recs + (long)g * REC))[part];
        }
        __syncthreads();
        for (int b2 = 0; b2 < nb; ++b2) {
            int4 bx = s_box[b2];                       // 16B broadcast read
            bool inbox = (abs(pix - bx.x) <= bx.w)
                      && (abs(piy - bx.y) <= bx.w)
                      && (abs(piz - bx.z) <= bx.w);
            if (__ballot(inbox) == 0ull) continue;     // wave-uniform skip
            const float* r = s_rec[b2];
            float dx = px - r[0], dy = py - r[1], dz = pz - r[2];
            // exponent (base-2) = log2(opac) - 0.5*log2e*quad, via 9 FMAs
            float e2 = r[3];
            e2 = fmaf(r[4], dx * dx, e2);
            e2 = fmaf(r[5], dy * dy, e2);
            e2 = fmaf(r[6], dz * dz, e2);
            e2 = fmaf(r[7], dx * dy, e2);
            e2 = fmaf(r[8], dy * dz, e2);
            e2 = fmaf(r[9], dx * dz, e2);
            float w = exp2f(e2);
            w = inbox ? w : 0.0f;
#pragma unroll
            for (int cc = 0; cc < C_N; ++cc)
                acc[cc] = fmaf(w, r[10 + cc], acc[cc]);
        }
    }

    // --- write out [N, C] fp32 ---
    const int n = gi * (WW * DD) + gj * DD + k;
    float* op = out + (long)n * C_N;
#pragma unroll
    for (int cc = 0; cc < C_N; ++cc) op[cc] = acc[cc];
}

extern "C" void kernel_launch(void* const* d_in, const int* in_sizes, int n_in,
                              void* d_out, int out_size, void* d_ws, size_t ws_size,
                              hipStream_t stream) {
    const float* means  = (const float*)d_in[1];
    const float* opac   = (const float*)d_in[2];
    const float* sem    = (const float*)d_in[3];
    const float* scales = (const float*)d_in[4];
    const float* cov    = (const float*)d_in[5];
    const float* origin = (const float*)d_in[6];
    float* out  = (float*)d_out;
    float* recs = (float*)d_ws;                       // 2048*24*4 = 192 KiB
    int4*  boxes = (int4*)((char*)d_ws + P_N * REC * sizeof(float));  // +32 KiB

    precompute_kernel<<<(P_N + 255) / 256, 256, 0, stream>>>(
        means, opac, sem, scales, cov, origin, recs, boxes);
    agg_kernel<<<(HH / 4) * (WW / 4) * (DD / ZCH), TPB, 0, stream>>>(
        recs, boxes, origin, out);
}